// Round 11
// baseline (313.355 us; speedup 1.0000x reference)
//
#include <hip/hip_runtime.h>
#include <hip/hip_bf16.h>

// ---------------------------------------------------------------------------
// NonLocal block + FC, MI355X (gfx950).
// out = (mean_n(x) + w_w @ ybar + w_b) @ fc_w^T + fc_b
//   ybar = g_w @ xg + g_b ;  xg[b,c] = sum_n abar[b,n] x[b,c,n]
//   abar[b,m] = mean_n softmax_row(f)[n,m],  f = theta @ phi^T
// |f| <~ 60 -> exp without max-subtraction is fp32-safe; e stored bf16.
// R5: XCD remaps. R6: K-slot XOR swizzle (conflicts 6.8M->0). R7: 2-phase
// dbuf 128^2 GEMM core (structure ceiling ~20-30% MfmaUtil; 8-phase port
// judged too race-risky for one-shot rounds). R10: short8 tail + 1-phase
// epilogues. R11: recip fused into abar, xbar moved to k_xg (transpose is
// pure copy), pad stores skipped (pad outputs provably never read).
// ---------------------------------------------------------------------------

#define BATCH 16
#define CIN   1024
#define CINT  512
#define NSP   1568      // 8*14*14
#define NPAD  1664      // 13*128
#define NTIL  13
#define NCLS  13

using bf16 = __hip_bfloat16;
typedef __attribute__((ext_vector_type(8))) short short8;
typedef __attribute__((ext_vector_type(4))) float f32x4;

#define DEVI static __device__ __forceinline__

DEVI void gload16(const void* g, void* l) {
  __builtin_amdgcn_global_load_lds((const __attribute__((address_space(1))) void*)g,
                                   (__attribute__((address_space(3))) void*)l, 16, 0, 0);
}

DEVI float wave_sum(float v) {
#pragma unroll
  for (int m = 32; m; m >>= 1) v += __shfl_xor(v, m);
  return v;
}

DEVI short f2bf(float f) {
  union { __hip_bfloat16 h; short s; } u;
  u.h = __float2bfloat16(f);
  return u.s;
}
DEVI float bf2f(short s) {
  union { float f; unsigned u; } x;
  x.u = ((unsigned)(unsigned short)s) << 16;
  return x.f;
}

// ---- K1: transpose x[b][c][n] fp32 -> xt[b][n][c] bf16 (pure copy) ---------
// grid (52, 8, 16) block 256. n-tiles >= 49 are all-pad (zero-filled).
__global__ __launch_bounds__(256) void k_transpose(const float* __restrict__ x,
                                                   bf16* __restrict__ xt) {
  __shared__ float t[128 * 37];
  const int b = blockIdx.z;
  const int n0 = blockIdx.x * 32;
  const int c0 = blockIdx.y * 128;
  const int tid = threadIdx.x;
  const float* xb = x + (size_t)b * CIN * NSP;
  const bool pad = (n0 >= NSP);
#pragma unroll
  for (int it = 0; it < 4; ++it) {
    const int slot = it * 256 + tid;
    const int cr = slot >> 3;       // 0..127
    const int q = slot & 7;         // 0..7
    float4 v = {0.f, 0.f, 0.f, 0.f};
    if (!pad) v = *(const float4*)(xb + (size_t)(c0 + cr) * NSP + n0 + q * 4);
    t[cr * 37 + q * 4 + 0] = v.x;
    t[cr * 37 + q * 4 + 1] = v.y;
    t[cr * 37 + q * 4 + 2] = v.z;
    t[cr * 37 + q * 4 + 3] = v.w;
  }
  __syncthreads();
  bf16* xo = xt + (size_t)b * NPAD * CIN;
#pragma unroll
  for (int it = 0; it < 2; ++it) {
    const int slot = it * 256 + tid;
    const int n = slot >> 4;        // 0..31
    const int seg = slot & 15;      // 0..15
    short8 o;
#pragma unroll
    for (int k = 0; k < 8; ++k) o[k] = f2bf(t[(seg * 8 + k) * 37 + n]);
    *(short8*)(xo + (size_t)(n0 + n) * CIN + c0 + seg * 8) = o;
  }
}

// ---- K1b: theta_w / phi_w fp32 -> wb bf16 [1024][1024] ---------------------
__global__ void k_wconv(const float* __restrict__ thw, const float* __restrict__ phw,
                        bf16* __restrict__ wb) {
  const int i4 = (blockIdx.x * 256 + threadIdx.x) * 4;
  const float* s = (i4 < 512 * 1024) ? (thw + i4) : (phw + (i4 - 512 * 1024));
  const float4 v = *(const float4*)s;
  wb[i4 + 0] = __float2bfloat16(v.x);
  wb[i4 + 1] = __float2bfloat16(v.y);
  wb[i4 + 2] = __float2bfloat16(v.z);
  wb[i4 + 3] = __float2bfloat16(v.w);
}

// ---- shared 128x128 bf16 BT-GEMM core: R6 swizzle + R7 2-phase dbuf --------
template <int LDK>
DEVI void gemm128_bt(const bf16* Ag, const bf16* Bg, bf16* lds,
                     f32x4 acc[4][4]) {
  const int tid = threadIdx.x;
  const int lane = tid & 63;
  const int w = tid >> 6;
  const int wr = (w >> 1) * 64;
  const int wc = (w & 1) * 64;
  const int kc_src8 = ((lane & 3) ^ ((lane >> 3) & 3)) * 8;
  const int kc_rd8 = (((lane >> 4) ^ ((lane >> 1) & 3))) * 8;
  constexpr int NT = LDK / 32;   // 32 (proj) or 16 (fgemm), even

  auto STAGE = [&](int buf, int ks) {
    bf16* lA = lds + buf * 8192;
    bf16* lB = lA + 4096;
#pragma unroll
    for (int it = 0; it < 2; ++it) {
      const int ch = w * 64 + it * 256 + lane;
      const int row = ch >> 2;
      const int lbase = (w * 64 + it * 256) * 8;   // wave-uniform LDS base
      gload16(Ag + (size_t)row * LDK + ks * 32 + kc_src8, lA + lbase);
      gload16(Bg + (size_t)row * LDK + ks * 32 + kc_src8, lB + lbase);
    }
  };
  auto COMPUTE = [&](int buf) {
    const bf16* lA = lds + buf * 8192;
    const bf16* lB = lA + 4096;
    short8 af[4], bfr[4];
#pragma unroll
    for (int i = 0; i < 4; ++i)
      af[i] = *(const short8*)(lA + (wr + i * 16 + (lane & 15)) * 32 + kc_rd8);
#pragma unroll
    for (int i = 0; i < 4; ++i)
      bfr[i] = *(const short8*)(lB + (wc + i * 16 + (lane & 15)) * 32 + kc_rd8);
#pragma unroll
    for (int m = 0; m < 4; ++m)
#pragma unroll
      for (int n = 0; n < 4; ++n)
        acc[m][n] = __builtin_amdgcn_mfma_f32_16x16x32_bf16(af[m], bfr[n], acc[m][n], 0, 0, 0);
  };

  STAGE(0, 0);
  __syncthreads();
  int ks = 0;
#pragma unroll 1
  while (ks < NT - 2) {
    STAGE(1, ks + 1);
    COMPUTE(0);
    __syncthreads();
    STAGE(0, ks + 2);
    COMPUTE(1);
    __syncthreads();
    ks += 2;
  }
  STAGE(1, NT - 1);
  COMPUTE(0);
  __syncthreads();
  COMPUTE(1);
  // no trailing sync: callers barrier before reusing lds.
}

// ---- K3: theta/phi projections. 1-D grid 1664, XCD-aware decode ------------
__global__ __launch_bounds__(256) void k_proj(const bf16* __restrict__ xt,
                                              const bf16* __restrict__ wb,
                                              const float* __restrict__ thb,
                                              const float* __restrict__ phb,
                                              bf16* __restrict__ th,
                                              bf16* __restrict__ ph) {
  __shared__ bf16 smem[16384];  // 32 KB: dbuf in GEMM, full 128x128 stage after
  const int id = blockIdx.x;          // 0..1663
  const int rcls = id & 7;
  const int q = id >> 3;              // 0..207
  const int bm = (q >> 3) * 8 + rcls; // 0..207, XCD = bm % 8
  const int bo = q & 7;               // 0..7

  f32x4 acc[4][4];
  const f32x4 z = {0.f, 0.f, 0.f, 0.f};
#pragma unroll
  for (int m = 0; m < 4; ++m)
#pragma unroll
    for (int n = 0; n < 4; ++n) acc[m][n] = z;

  gemm128_bt<CIN>(xt + (size_t)bm * 128 * CIN, wb + (size_t)bo * 128 * CIN,
                  smem, acc);

  const int tid = threadIdx.x;
  const int lane = tid & 63;
  const int w = tid >> 6;
  const int wr = (w >> 1) * 64;
  const int wc = (w & 1) * 64;
  const float* bias = (bo < 4) ? thb : phb;
  bf16* outb = (bo < 4) ? th : ph;
  const int obase = (bo & 3) * 128;
  const bool mtail = (bm % 13) == 12;  // tile contains pad rows (local r>=32)
  __syncthreads();                     // GEMM lds reads done
#pragma unroll
  for (int m = 0; m < 4; ++m)
#pragma unroll
    for (int n = 0; n < 4; ++n) {
      const int col = wc + n * 16 + (lane & 15);
      const float bv = bias[obase + col];
#pragma unroll
      for (int j = 0; j < 4; ++j) {
        const int row = wr + m * 16 + (lane >> 4) * 4 + j;   // 0..127
        smem[row * 128 + (col ^ ((row & 7) << 3))] =
            __float2bfloat16(acc[m][n][j] + bv);
      }
    }
  __syncthreads();
#pragma unroll
  for (int it = 0; it < 8; ++it) {
    const int slot = it * 256 + tid;
    const int r = slot >> 4;          // 0..127
    const int seg = slot & 15;
    if (mtail && r >= 32) continue;   // pad rows: never read downstream as output
    const short8 v = *(const short8*)(smem + r * 128 + ((seg ^ (r & 7)) << 3));
    *(short8*)(outb + (size_t)(bm * 128 + r) * CINT + obase + seg * 8) = v;
  }
}

// ---- K4: e = exp(theta @ phi^T) bf16 + per-tile row sums -------------------
// 1-D grid 2704, XCD-aware decode: batches {b: b%8==r} on XCD r.
// Pad outputs (rows/cols >= 1568) are skipped: k_abar reads n,m < 1568 only.
__global__ __launch_bounds__(256) void k_fgemm(const bf16* __restrict__ th,
                                               const bf16* __restrict__ ph,
                                               bf16* __restrict__ eb,
                                               float* __restrict__ psum) {
  __shared__ bf16 smem[16384];
  __shared__ float rsum2[2][128];
  const int id = blockIdx.x;          // 0..2703
  const int rcls = id & 7;
  const int q = id >> 3;              // 0..337
  const int bloc = q / 169;           // 0..1
  const int t = q - bloc * 169;       // 0..168
  const int b = bloc * 8 + rcls;      // 0..15, XCD = b % 8
  const int bm = t / 13;
  const int bn = t - bm * 13;

  f32x4 acc[4][4];
  const f32x4 z = {0.f, 0.f, 0.f, 0.f};
#pragma unroll
  for (int m = 0; m < 4; ++m)
#pragma unroll
    for (int n = 0; n < 4; ++n) acc[m][n] = z;

  gemm128_bt<CINT>(th + ((size_t)b * NPAD + bm * 128) * CINT,
                   ph + ((size_t)b * NPAD + bn * 128) * CINT,
                   smem, acc);

  const int tid = threadIdx.x;
  const int lane = tid & 63;
  const int w = tid >> 6;
  const int wr = (w >> 1) * 64;
  const int wc = (w & 1) * 64;
  bf16* ebb = eb + ((size_t)b * NPAD + bm * 128) * NPAD + bn * 128;
  __syncthreads();                    // GEMM lds reads done
#pragma unroll
  for (int m = 0; m < 4; ++m)
#pragma unroll
    for (int j = 0; j < 4; ++j) {
      const int row = wr + m * 16 + (lane >> 4) * 4 + j;     // 0..127
      float ps = 0.f;
#pragma unroll
      for (int n = 0; n < 4; ++n) {
        const int col = wc + n * 16 + (lane & 15);
        const float ev = __expf(acc[m][n][j]);
        smem[row * 128 + (col ^ ((row & 7) << 3))] = __float2bfloat16(ev);
        if (bn * 128 + col < NSP) ps += ev;                  // mask pad columns
      }
      ps += __shfl_xor(ps, 1);
      ps += __shfl_xor(ps, 2);
      ps += __shfl_xor(ps, 4);
      ps += __shfl_xor(ps, 8);
      if ((lane & 15) == 0) rsum2[w & 1][row] = ps;
    }
  __syncthreads();
  if (tid < 128 && (bm != 12 || tid < 32))   // skip pad psum rows (never read)
    psum[((size_t)b * NTIL + bn) * NPAD + bm * 128 + tid] =
        rsum2[0][tid] + rsum2[1][tid];
#pragma unroll
  for (int it = 0; it < 8; ++it) {
    const int slot = it * 256 + tid;
    const int r = slot >> 4;          // 0..127
    const int seg = slot & 15;
    if (bm == 12 && r >= 32) continue;      // pad rows
    if (bn == 12 && seg >= 4) continue;     // pad cols
    const short8 v = *(const short8*)(smem + r * 128 + ((seg ^ (r & 7)) << 3));
    *(short8*)(ebb + (size_t)r * NPAD + seg * 8) = v;
  }
}

// ---- K5: abar[b][m] = (1/N) sum_n e[n,m] / rowsum[n]  (rinv fused) ---------
// grid (32, 16): x = n-slice of 49 rows (32*49 == 1568), y = b.
// threads 0..195 each own 8 m's (196*8 == 1568 exact).
__global__ void k_abar(const bf16* __restrict__ eb, const float* __restrict__ psum,
                       float* __restrict__ abar) {
  __shared__ float srinv[49];
  const int b = blockIdx.y;
  const int n0 = blockIdx.x * 49;
  const int tid = threadIdx.x;
  if (tid < 49) {
    float s = 0.f;
#pragma unroll
    for (int t = 0; t < NTIL; ++t)
      s += psum[((size_t)b * NTIL + t) * NPAD + n0 + tid];
    srinv[tid] = 1.0f / s;
  }
  __syncthreads();
  const int m0 = tid * 8;
  if (m0 >= NSP) return;
  const bf16* fb = eb + (size_t)b * NPAD * NPAD;
  float a[8];
#pragma unroll
  for (int k = 0; k < 8; ++k) a[k] = 0.f;
#pragma unroll 1
  for (int n = n0; n < n0 + 49; ++n) {
    const float iS = srinv[n - n0];
    const short8 v = *(const short8*)(fb + (size_t)n * NPAD + m0);
#pragma unroll
    for (int k = 0; k < 8; ++k) a[k] += bf2f(v[k]) * iS;
  }
#pragma unroll
  for (int k = 0; k < 8; ++k)
    atomicAdd(&abar[b * NSP + m0 + k], a[k] * (1.0f / NSP));
}

// ---- K6: xg[b][c] = sum_n abar[b][n] xt[b][n][c]; xbar fused (bf16 source) -
// grid (16, 16): x = n-slice of 98 rows, y = b; block 128, 8 c's/thread.
__global__ __launch_bounds__(128) void k_xg(const bf16* __restrict__ xt,
                                            const float* __restrict__ abar,
                                            float* __restrict__ xg,
                                            float* __restrict__ xbar) {
  const int b = blockIdx.y;
  const int n0 = blockIdx.x * 98;
  const int c0 = threadIdx.x * 8;     // 128*8 == 1024 exact
  const bf16* xb = xt + (size_t)b * NPAD * CIN;
  float a[8], s[8];
#pragma unroll
  for (int k = 0; k < 8; ++k) { a[k] = 0.f; s[k] = 0.f; }
#pragma unroll 1
  for (int n = n0; n < n0 + 98; ++n) {
    const float wgt = abar[b * NSP + n];
    const short8 v = *(const short8*)(xb + (size_t)n * CIN + c0);
#pragma unroll
    for (int k = 0; k < 8; ++k) {
      const float f = bf2f(v[k]);
      a[k] += f * wgt;
      s[k] += f;
    }
  }
#pragma unroll
  for (int k = 0; k < 8; ++k) {
    atomicAdd(&xg[b * CIN + c0 + k], a[k]);
    atomicAdd(&xbar[b * CIN + c0 + k], s[k] * (1.0f / NSP));
  }
}

// ---- K7a: ybar[b][d] = g_w[d,:] @ xg[b,:] + g_b[d] -------------------------
__global__ __launch_bounds__(64) void k_ybar(const float* __restrict__ gw,
                                             const float* __restrict__ gb,
                                             const float* __restrict__ xg,
                                             float* __restrict__ syb) {
  const int d = blockIdx.x;          // 512 blocks
  const int lane = threadIdx.x;
  const float4* wr = (const float4*)(gw + (size_t)d * CIN);
  float4 wv[4];
#pragma unroll
  for (int k = 0; k < 4; ++k) wv[k] = wr[k * 64 + lane];
  const float bv = gb[d];
#pragma unroll 1
  for (int b = 0; b < BATCH; ++b) {
    const float4* xr = (const float4*)(xg + (size_t)b * CIN);
    float s = 0.f;
#pragma unroll
    for (int k = 0; k < 4; ++k) {
      const float4 xv = xr[k * 64 + lane];
      s += wv[k].x * xv.x + wv[k].y * xv.y + wv[k].z * xv.z + wv[k].w * xv.w;
    }
    s = wave_sum(s);
    if (lane == 0) syb[b * CINT + d] = s + bv;
  }
}

// ---- K7b: spool[b][c] = xbar + w_b + w_w[c,:] @ ybar[b,:] ------------------
__global__ __launch_bounds__(64) void k_spool(const float* __restrict__ ww,
                                              const float* __restrict__ wbias,
                                              const float* __restrict__ xbar,
                                              const float* __restrict__ syb,
                                              float* __restrict__ spool) {
  const int c = blockIdx.x;          // 1024 blocks
  const int lane = threadIdx.x;
  const float4* wr = (const float4*)(ww + (size_t)c * CINT);
  float4 wv[2];
#pragma unroll
  for (int k = 0; k < 2; ++k) wv[k] = wr[k * 64 + lane];
  const float bv = wbias[c];
#pragma unroll 1
  for (int b = 0; b < BATCH; ++b) {
    const float4* yr = (const float4*)(syb + (size_t)b * CINT);
    float s = 0.f;
#pragma unroll
    for (int k = 0; k < 2; ++k) {
      const float4 yv = yr[k * 64 + lane];
      s += wv[k].x * yv.x + wv[k].y * yv.y + wv[k].z * yv.z + wv[k].w * yv.w;
    }
    s = wave_sum(s);
    if (lane == 0) spool[b * CIN + c] = s + bv + xbar[b * CIN + c];
  }
}

// ---- K7c: out = spool @ fc_w^T + fc_b --------------------------------------
__global__ __launch_bounds__(64) void k_out(const float* __restrict__ spool,
                                            const float* __restrict__ fcw,
                                            const float* __restrict__ fcb,
                                            float* __restrict__ out) {
  const int b = blockIdx.x;          // 16 blocks
  const int lane = threadIdx.x;
  const float4* pr = (const float4*)(spool + (size_t)b * CIN);
  float4 pv[4];
#pragma unroll
  for (int k = 0; k < 4; ++k) pv[k] = pr[k * 64 + lane];
#pragma unroll 1
  for (int cls = 0; cls < NCLS; ++cls) {
    const float4* wr = (const float4*)(fcw + (size_t)cls * CIN);
    float s = 0.f;
#pragma unroll
    for (int k = 0; k < 4; ++k) {
      const float4 wv = wr[k * 64 + lane];
      s += wv.x * pv[k].x + wv.y * pv[k].y + wv.z * pv[k].z + wv.w * pv[k].w;
    }
    s = wave_sum(s);
    if (lane == 0) out[b * NCLS + cls] = s + fcb[cls];
  }
}

// ---------------------------------------------------------------------------
extern "C" void kernel_launch(void* const* d_in, const int* in_sizes, int n_in,
                              void* d_out, int out_size, void* d_ws, size_t ws_size,
                              hipStream_t stream) {
  const float* x    = (const float*)d_in[0];
  const float* g_w  = (const float*)d_in[1];
  const float* g_b  = (const float*)d_in[2];
  const float* th_w = (const float*)d_in[3];
  const float* th_b = (const float*)d_in[4];
  const float* ph_w = (const float*)d_in[5];
  const float* ph_b = (const float*)d_in[6];
  const float* w_w  = (const float*)d_in[7];
  const float* w_b  = (const float*)d_in[8];
  const float* fc_w = (const float*)d_in[9];
  const float* fc_b = (const float*)d_in[10];
  float* out = (float*)d_out;

  char* ws = (char*)d_ws;
  size_t off = 0;
  auto carve = [&](size_t bytes) {
    void* p = ws + off;
    off = (off + bytes + 255) & ~(size_t)255;
    return p;
  };
  bf16*  xt    = (bf16*)carve((size_t)BATCH * NPAD * CIN * 2);    // 54.5 MB
  bf16*  wb    = (bf16*)carve((size_t)1024 * 1024 * 2);           //  2 MB
  bf16*  th    = (bf16*)carve((size_t)BATCH * NPAD * CINT * 2);   // 27.3 MB
  bf16*  ph    = (bf16*)carve((size_t)BATCH * NPAD * CINT * 2);   // 27.3 MB
  bf16*  eb    = (bf16*)carve((size_t)BATCH * NPAD * NPAD * 2);   // 88.6 MB
  float* psum  = (float*)carve((size_t)BATCH * NTIL * NPAD * 4);  //  1.4 MB
  float* abar  = (float*)carve((size_t)BATCH * NSP * 4);
  float* xbar  = (float*)carve((size_t)BATCH * CIN * 4);
  float* xg    = (float*)carve((size_t)BATCH * CIN * 4);
  float* syb   = (float*)carve((size_t)BATCH * CINT * 4);
  float* spool = (float*)carve((size_t)BATCH * CIN * 4);
  (void)ws_size; (void)in_sizes; (void)n_in; (void)out_size;

  hipMemsetAsync(abar, 0, (size_t)BATCH * NSP * 4, stream);
  hipMemsetAsync(xbar, 0, (size_t)BATCH * CIN * 4, stream);
  hipMemsetAsync(xg,   0, (size_t)BATCH * CIN * 4, stream);

  k_transpose<<<dim3(52, 8, 16), 256, 0, stream>>>(x, xt);
  k_wconv<<<1024, 256, 0, stream>>>(th_w, ph_w, wb);
  k_proj<<<1664, 256, 0, stream>>>(xt, wb, th_b, ph_b, th, ph);
  k_fgemm<<<2704, 256, 0, stream>>>(th, ph, eb, psum);
  k_abar<<<dim3(32, 16), 256, 0, stream>>>(eb, psum, abar);
  k_xg<<<dim3(16, 16), 128, 0, stream>>>(xt, abar, xg, xbar);
  k_ybar<<<512, 64, 0, stream>>>(g_w, g_b, xg, syb);
  k_spool<<<1024, 64, 0, stream>>>(w_w, w_b, xbar, syb, spool);
  k_out<<<16, 64, 0, stream>>>(spool, fc_w, fc_b, out);
}

// Round 12
// 298.782 us; speedup vs baseline: 1.0488x; 1.0488x over previous
//
#include <hip/hip_runtime.h>
#include <hip/hip_bf16.h>

// ---------------------------------------------------------------------------
// NonLocal block + FC, MI355X (gfx950).
// out = (mean_n(x) + w_w @ ybar + w_b) @ fc_w^T + fc_b
//   ybar = g_w @ xg + g_b ;  xg[b,c] = sum_n abar[b,n] x[b,c,n]
//   abar[b,m] = mean_n softmax_row(f)[n,m],  f = theta @ phi^T
// |f| <~ 60 -> exp without max-subtraction is fp32-safe; e stored bf16.
// R5: XCD remaps. R6: K-slot XOR swizzle (conflicts 6.8M->0). R7: 2-phase
// dbuf 128^2 GEMM core. R10: short8 tail + 1-phase epilogues (best: 297 us).
// R11 regressed (pad-skip branches + tail fusion package) -> reverted.
// R12: R10 + recip fused into k_abar only (one fewer dispatch, same math).
// ---------------------------------------------------------------------------

#define BATCH 16
#define CIN   1024
#define CINT  512
#define NSP   1568      // 8*14*14
#define NPAD  1664      // 13*128
#define NTIL  13
#define NCLS  13

using bf16 = __hip_bfloat16;
typedef __attribute__((ext_vector_type(8))) short short8;
typedef __attribute__((ext_vector_type(4))) float f32x4;

#define DEVI static __device__ __forceinline__

DEVI void gload16(const void* g, void* l) {
  __builtin_amdgcn_global_load_lds((const __attribute__((address_space(1))) void*)g,
                                   (__attribute__((address_space(3))) void*)l, 16, 0, 0);
}

DEVI float wave_sum(float v) {
#pragma unroll
  for (int m = 32; m; m >>= 1) v += __shfl_xor(v, m);
  return v;
}

DEVI short f2bf(float f) {
  union { __hip_bfloat16 h; short s; } u;
  u.h = __float2bfloat16(f);
  return u.s;
}
DEVI float bf2f(short s) {
  union { float f; unsigned u; } x;
  x.u = ((unsigned)(unsigned short)s) << 16;
  return x.f;
}

// ---- K1: transpose x[b][c][n] fp32 -> xt[b][n][c] bf16, fused xbar ---------
// grid (52, 8, 16) block 256. n-tiles >= 49 are all-pad (zero-filled).
__global__ __launch_bounds__(256) void k_transpose(const float* __restrict__ x,
                                                   bf16* __restrict__ xt,
                                                   float* __restrict__ xbar) {
  __shared__ float t[128 * 37];
  const int b = blockIdx.z;
  const int n0 = blockIdx.x * 32;
  const int c0 = blockIdx.y * 128;
  const int tid = threadIdx.x;
  const int lane = tid & 63;
  const float* xb = x + (size_t)b * CIN * NSP;
  const bool pad = (n0 >= NSP);
#pragma unroll
  for (int it = 0; it < 4; ++it) {
    const int slot = it * 256 + tid;
    const int cr = slot >> 3;       // 0..127
    const int q = slot & 7;         // 0..7
    float4 v = {0.f, 0.f, 0.f, 0.f};
    if (!pad) v = *(const float4*)(xb + (size_t)(c0 + cr) * NSP + n0 + q * 4);
    t[cr * 37 + q * 4 + 0] = v.x;
    t[cr * 37 + q * 4 + 1] = v.y;
    t[cr * 37 + q * 4 + 2] = v.z;
    t[cr * 37 + q * 4 + 3] = v.w;
    float s = v.x + v.y + v.z + v.w;
    s += __shfl_xor(s, 1);
    s += __shfl_xor(s, 2);
    s += __shfl_xor(s, 4);
    if ((lane & 7) == 0 && !pad)
      atomicAdd(&xbar[b * CIN + c0 + cr], s * (1.0f / NSP));
  }
  __syncthreads();
  bf16* xo = xt + (size_t)b * NPAD * CIN;
#pragma unroll
  for (int it = 0; it < 2; ++it) {
    const int slot = it * 256 + tid;
    const int n = slot >> 4;        // 0..31
    const int seg = slot & 15;      // 0..15
    short8 o;
#pragma unroll
    for (int k = 0; k < 8; ++k) o[k] = f2bf(t[(seg * 8 + k) * 37 + n]);
    *(short8*)(xo + (size_t)(n0 + n) * CIN + c0 + seg * 8) = o;
  }
}

// ---- K1b: theta_w / phi_w fp32 -> wb bf16 [1024][1024] ---------------------
__global__ void k_wconv(const float* __restrict__ thw, const float* __restrict__ phw,
                        bf16* __restrict__ wb) {
  const int i4 = (blockIdx.x * 256 + threadIdx.x) * 4;
  const float* s = (i4 < 512 * 1024) ? (thw + i4) : (phw + (i4 - 512 * 1024));
  const float4 v = *(const float4*)s;
  wb[i4 + 0] = __float2bfloat16(v.x);
  wb[i4 + 1] = __float2bfloat16(v.y);
  wb[i4 + 2] = __float2bfloat16(v.z);
  wb[i4 + 3] = __float2bfloat16(v.w);
}

// ---- shared 128x128 bf16 BT-GEMM core: R6 swizzle + R7 2-phase dbuf --------
// LDS slot (row, kc) holds global (row, kc ^ ((row>>1)&3)); staging keeps
// gload_lds dest LINEAR and pre-swizzles the per-lane GLOBAL column; reads
// apply the same involution (lane-only expressions, zero extra VALU).
// Double buffer: lds[0..8191] = buf0 (A|B), lds[8192..16383] = buf1 (A|B).
template <int LDK>
DEVI void gemm128_bt(const bf16* Ag, const bf16* Bg, bf16* lds,
                     f32x4 acc[4][4]) {
  const int tid = threadIdx.x;
  const int lane = tid & 63;
  const int w = tid >> 6;
  const int wr = (w >> 1) * 64;
  const int wc = (w & 1) * 64;
  const int kc_src8 = ((lane & 3) ^ ((lane >> 3) & 3)) * 8;
  const int kc_rd8 = (((lane >> 4) ^ ((lane >> 1) & 3))) * 8;
  constexpr int NT = LDK / 32;   // 32 (proj) or 16 (fgemm), even

  auto STAGE = [&](int buf, int ks) {
    bf16* lA = lds + buf * 8192;
    bf16* lB = lA + 4096;
#pragma unroll
    for (int it = 0; it < 2; ++it) {
      const int ch = w * 64 + it * 256 + lane;
      const int row = ch >> 2;
      const int lbase = (w * 64 + it * 256) * 8;   // wave-uniform LDS base
      gload16(Ag + (size_t)row * LDK + ks * 32 + kc_src8, lA + lbase);
      gload16(Bg + (size_t)row * LDK + ks * 32 + kc_src8, lB + lbase);
    }
  };
  auto COMPUTE = [&](int buf) {
    const bf16* lA = lds + buf * 8192;
    const bf16* lB = lA + 4096;
    short8 af[4], bfr[4];
#pragma unroll
    for (int i = 0; i < 4; ++i)
      af[i] = *(const short8*)(lA + (wr + i * 16 + (lane & 15)) * 32 + kc_rd8);
#pragma unroll
    for (int i = 0; i < 4; ++i)
      bfr[i] = *(const short8*)(lB + (wc + i * 16 + (lane & 15)) * 32 + kc_rd8);
#pragma unroll
    for (int m = 0; m < 4; ++m)
#pragma unroll
      for (int n = 0; n < 4; ++n)
        acc[m][n] = __builtin_amdgcn_mfma_f32_16x16x32_bf16(af[m], bfr[n], acc[m][n], 0, 0, 0);
  };

  STAGE(0, 0);
  __syncthreads();
  int ks = 0;
#pragma unroll 1
  while (ks < NT - 2) {
    STAGE(1, ks + 1);
    COMPUTE(0);
    __syncthreads();
    STAGE(0, ks + 2);
    COMPUTE(1);
    __syncthreads();
    ks += 2;
  }
  STAGE(1, NT - 1);
  COMPUTE(0);
  __syncthreads();
  COMPUTE(1);
  // no trailing sync: callers barrier before reusing lds.
}

// ---- K3: theta/phi projections. 1-D grid 1664, XCD-aware decode ------------
// Single-phase epilogue: all 4 waves stage their quadrant into the full
// 128x128 (32 KB) smem concurrently, then one coalesced store pass.
__global__ __launch_bounds__(256) void k_proj(const bf16* __restrict__ xt,
                                              const bf16* __restrict__ wb,
                                              const float* __restrict__ thb,
                                              const float* __restrict__ phb,
                                              bf16* __restrict__ th,
                                              bf16* __restrict__ ph) {
  __shared__ bf16 smem[16384];  // 32 KB: dbuf in GEMM, full 128x128 stage after
  const int id = blockIdx.x;          // 0..1663
  const int rcls = id & 7;
  const int q = id >> 3;              // 0..207
  const int bm = (q >> 3) * 8 + rcls; // 0..207, XCD = bm % 8
  const int bo = q & 7;               // 0..7

  f32x4 acc[4][4];
  const f32x4 z = {0.f, 0.f, 0.f, 0.f};
#pragma unroll
  for (int m = 0; m < 4; ++m)
#pragma unroll
    for (int n = 0; n < 4; ++n) acc[m][n] = z;

  gemm128_bt<CIN>(xt + (size_t)bm * 128 * CIN, wb + (size_t)bo * 128 * CIN,
                  smem, acc);

  const int tid = threadIdx.x;
  const int lane = tid & 63;
  const int w = tid >> 6;
  const int wr = (w >> 1) * 64;
  const int wc = (w & 1) * 64;
  const float* bias = (bo < 4) ? thb : phb;
  bf16* outb = (bo < 4) ? th : ph;
  const int obase = (bo & 3) * 128;
  __syncthreads();                    // GEMM lds reads done
#pragma unroll
  for (int m = 0; m < 4; ++m)
#pragma unroll
    for (int n = 0; n < 4; ++n) {
      const int col = wc + n * 16 + (lane & 15);
      const float bv = bias[obase + col];
#pragma unroll
      for (int j = 0; j < 4; ++j) {
        const int row = wr + m * 16 + (lane >> 4) * 4 + j;   // 0..127
        smem[row * 128 + (col ^ ((row & 7) << 3))] =
            __float2bfloat16(acc[m][n][j] + bv);
      }
    }
  __syncthreads();
#pragma unroll
  for (int it = 0; it < 8; ++it) {
    const int slot = it * 256 + tid;
    const int r = slot >> 4;          // 0..127
    const int seg = slot & 15;
    const short8 v = *(const short8*)(smem + r * 128 + ((seg ^ (r & 7)) << 3));
    *(short8*)(outb + (size_t)(bm * 128 + r) * CINT + obase + seg * 8) = v;
  }
}

// ---- K4: e = exp(theta @ phi^T) bf16 + per-tile row sums -------------------
// 1-D grid 2704, XCD-aware decode: batches {b: b%8==r} on XCD r.
// Single-phase epilogue: all 4 waves exp+stage concurrently (rsum2 slots
// disjoint: [w&1][(w>>1)*64 + lr]).
__global__ __launch_bounds__(256) void k_fgemm(const bf16* __restrict__ th,
                                               const bf16* __restrict__ ph,
                                               bf16* __restrict__ eb,
                                               float* __restrict__ psum) {
  __shared__ bf16 smem[16384];
  __shared__ float rsum2[2][128];
  const int id = blockIdx.x;          // 0..2703
  const int rcls = id & 7;
  const int q = id >> 3;              // 0..337
  const int bloc = q / 169;           // 0..1
  const int t = q - bloc * 169;       // 0..168
  const int b = bloc * 8 + rcls;      // 0..15, XCD = b % 8
  const int bm = t / 13;
  const int bn = t - bm * 13;

  f32x4 acc[4][4];
  const f32x4 z = {0.f, 0.f, 0.f, 0.f};
#pragma unroll
  for (int m = 0; m < 4; ++m)
#pragma unroll
    for (int n = 0; n < 4; ++n) acc[m][n] = z;

  gemm128_bt<CINT>(th + ((size_t)b * NPAD + bm * 128) * CINT,
                   ph + ((size_t)b * NPAD + bn * 128) * CINT,
                   smem, acc);

  const int tid = threadIdx.x;
  const int lane = tid & 63;
  const int w = tid >> 6;
  const int wr = (w >> 1) * 64;
  const int wc = (w & 1) * 64;
  bf16* ebb = eb + ((size_t)b * NPAD + bm * 128) * NPAD + bn * 128;
  __syncthreads();                    // GEMM lds reads done
#pragma unroll
  for (int m = 0; m < 4; ++m)
#pragma unroll
    for (int j = 0; j < 4; ++j) {
      const int row = wr + m * 16 + (lane >> 4) * 4 + j;     // 0..127
      float ps = 0.f;
#pragma unroll
      for (int n = 0; n < 4; ++n) {
        const int col = wc + n * 16 + (lane & 15);
        const float ev = __expf(acc[m][n][j]);
        smem[row * 128 + (col ^ ((row & 7) << 3))] = __float2bfloat16(ev);
        if (bn * 128 + col < NSP) ps += ev;                  // mask pad columns
      }
      ps += __shfl_xor(ps, 1);
      ps += __shfl_xor(ps, 2);
      ps += __shfl_xor(ps, 4);
      ps += __shfl_xor(ps, 8);
      if ((lane & 15) == 0) rsum2[w & 1][row] = ps;
    }
  __syncthreads();
  if (tid < 128)
    psum[((size_t)b * NTIL + bn) * NPAD + bm * 128 + tid] =
        rsum2[0][tid] + rsum2[1][tid];
#pragma unroll
  for (int it = 0; it < 8; ++it) {
    const int slot = it * 256 + tid;
    const int r = slot >> 4;          // 0..127
    const int seg = slot & 15;
    const short8 v = *(const short8*)(smem + r * 128 + ((seg ^ (r & 7)) << 3));
    *(short8*)(ebb + (size_t)r * NPAD + seg * 8) = v;
  }
}

// ---- K5: abar[b][m] = (1/N) sum_n e[n,m] / rowsum[n]  (recip fused) --------
// grid (32, 16): x = n-slice of 49 rows (32*49 == 1568), y = b.
// threads 0..195 each own 8 m's (196*8 == 1568 exact).
__global__ void k_abar(const bf16* __restrict__ eb, const float* __restrict__ psum,
                       float* __restrict__ abar) {
  __shared__ float srinv[49];
  const int b = blockIdx.y;
  const int n0 = blockIdx.x * 49;
  const int tid = threadIdx.x;
  if (tid < 49) {
    float s = 0.f;
#pragma unroll
    for (int t = 0; t < NTIL; ++t)
      s += psum[((size_t)b * NTIL + t) * NPAD + n0 + tid];
    srinv[tid] = 1.0f / s;
  }
  __syncthreads();
  const int m0 = tid * 8;
  if (m0 >= NSP) return;
  const bf16* fb = eb + (size_t)b * NPAD * NPAD;
  float a[8];
#pragma unroll
  for (int k = 0; k < 8; ++k) a[k] = 0.f;
#pragma unroll 1
  for (int n = n0; n < n0 + 49; ++n) {
    const float iS = srinv[n - n0];
    const short8 v = *(const short8*)(fb + (size_t)n * NPAD + m0);
#pragma unroll
    for (int k = 0; k < 8; ++k) a[k] += bf2f(v[k]) * iS;
  }
#pragma unroll
  for (int k = 0; k < 8; ++k)
    atomicAdd(&abar[b * NSP + m0 + k], a[k] * (1.0f / NSP));
}

// ---- K7: xg[b][c] = sum_n abar[b][n] * xt[b][n][c]  (short8 loads) ---------
// grid (16, 16): x = n-slice of 98 rows, y = b; block 128, 8 c's/thread.
__global__ __launch_bounds__(128) void k_xg(const bf16* __restrict__ xt,
                                            const float* __restrict__ abar,
                                            float* __restrict__ xg) {
  const int b = blockIdx.y;
  const int n0 = blockIdx.x * 98;
  const int c0 = threadIdx.x * 8;     // 128*8 == 1024 exact
  const bf16* xb = xt + (size_t)b * NPAD * CIN;
  float a[8];
#pragma unroll
  for (int k = 0; k < 8; ++k) a[k] = 0.f;
#pragma unroll 1
  for (int n = n0; n < n0 + 98; ++n) {
    const float wgt = abar[b * NSP + n];
    const short8 v = *(const short8*)(xb + (size_t)n * CIN + c0);
#pragma unroll
    for (int k = 0; k < 8; ++k) a[k] += bf2f(v[k]) * wgt;
  }
#pragma unroll
  for (int k = 0; k < 8; ++k)
    atomicAdd(&xg[b * CIN + c0 + k], a[k]);
}

// ---- K8a: ybar[b][d] = g_w[d,:] @ xg[b,:] + g_b[d] -------------------------
__global__ __launch_bounds__(64) void k_ybar(const float* __restrict__ gw,
                                             const float* __restrict__ gb,
                                             const float* __restrict__ xg,
                                             float* __restrict__ syb) {
  const int d = blockIdx.x;          // 512 blocks
  const int lane = threadIdx.x;
  const float4* wr = (const float4*)(gw + (size_t)d * CIN);
  float4 wv[4];
#pragma unroll
  for (int k = 0; k < 4; ++k) wv[k] = wr[k * 64 + lane];
  const float bv = gb[d];
#pragma unroll 1
  for (int b = 0; b < BATCH; ++b) {
    const float4* xr = (const float4*)(xg + (size_t)b * CIN);
    float s = 0.f;
#pragma unroll
    for (int k = 0; k < 4; ++k) {
      const float4 xv = xr[k * 64 + lane];
      s += wv[k].x * xv.x + wv[k].y * xv.y + wv[k].z * xv.z + wv[k].w * xv.w;
    }
    s = wave_sum(s);
    if (lane == 0) syb[b * CINT + d] = s + bv;
  }
}

// ---- K8b: spool[b][c] = xbar + w_b + w_w[c,:] @ ybar[b,:] ------------------
__global__ __launch_bounds__(64) void k_spool(const float* __restrict__ ww,
                                              const float* __restrict__ wbias,
                                              const float* __restrict__ xbar,
                                              const float* __restrict__ syb,
                                              float* __restrict__ spool) {
  const int c = blockIdx.x;          // 1024 blocks
  const int lane = threadIdx.x;
  const float4* wr = (const float4*)(ww + (size_t)c * CINT);
  float4 wv[2];
#pragma unroll
  for (int k = 0; k < 2; ++k) wv[k] = wr[k * 64 + lane];
  const float bv = wbias[c];
#pragma unroll 1
  for (int b = 0; b < BATCH; ++b) {
    const float4* yr = (const float4*)(syb + (size_t)b * CINT);
    float s = 0.f;
#pragma unroll
    for (int k = 0; k < 2; ++k) {
      const float4 yv = yr[k * 64 + lane];
      s += wv[k].x * yv.x + wv[k].y * yv.y + wv[k].z * yv.z + wv[k].w * yv.w;
    }
    s = wave_sum(s);
    if (lane == 0) spool[b * CIN + c] = s + bv + xbar[b * CIN + c];
  }
}

// ---- K8c: out = spool @ fc_w^T + fc_b --------------------------------------
__global__ __launch_bounds__(64) void k_out(const float* __restrict__ spool,
                                            const float* __restrict__ fcw,
                                            const float* __restrict__ fcb,
                                            float* __restrict__ out) {
  const int b = blockIdx.x;          // 16 blocks
  const int lane = threadIdx.x;
  const float4* pr = (const float4*)(spool + (size_t)b * CIN);
  float4 pv[4];
#pragma unroll
  for (int k = 0; k < 4; ++k) pv[k] = pr[k * 64 + lane];
#pragma unroll 1
  for (int cls = 0; cls < NCLS; ++cls) {
    const float4* wr = (const float4*)(fcw + (size_t)cls * CIN);
    float s = 0.f;
#pragma unroll
    for (int k = 0; k < 4; ++k) {
      const float4 wv = wr[k * 64 + lane];
      s += wv.x * pv[k].x + wv.y * pv[k].y + wv.z * pv[k].z + wv.w * pv[k].w;
    }
    s = wave_sum(s);
    if (lane == 0) out[b * NCLS + cls] = s + fcb[cls];
  }
}

// ---------------------------------------------------------------------------
extern "C" void kernel_launch(void* const* d_in, const int* in_sizes, int n_in,
                              void* d_out, int out_size, void* d_ws, size_t ws_size,
                              hipStream_t stream) {
  const float* x    = (const float*)d_in[0];
  const float* g_w  = (const float*)d_in[1];
  const float* g_b  = (const float*)d_in[2];
  const float* th_w = (const float*)d_in[3];
  const float* th_b = (const float*)d_in[4];
  const float* ph_w = (const float*)d_in[5];
  const float* ph_b = (const float*)d_in[6];
  const float* w_w  = (const float*)d_in[7];
  const float* w_b  = (const float*)d_in[8];
  const float* fc_w = (const float*)d_in[9];
  const float* fc_b = (const float*)d_in[10];
  float* out = (float*)d_out;

  char* ws = (char*)d_ws;
  size_t off = 0;
  auto carve = [&](size_t bytes) {
    void* p = ws + off;
    off = (off + bytes + 255) & ~(size_t)255;
    return p;
  };
  bf16*  xt    = (bf16*)carve((size_t)BATCH * NPAD * CIN * 2);    // 54.5 MB
  bf16*  wb    = (bf16*)carve((size_t)1024 * 1024 * 2);           //  2 MB
  bf16*  th    = (bf16*)carve((size_t)BATCH * NPAD * CINT * 2);   // 27.3 MB
  bf16*  ph    = (bf16*)carve((size_t)BATCH * NPAD * CINT * 2);   // 27.3 MB
  bf16*  eb    = (bf16*)carve((size_t)BATCH * NPAD * NPAD * 2);   // 88.6 MB
  float* psum  = (float*)carve((size_t)BATCH * NTIL * NPAD * 4);  //  1.4 MB
  float* abar  = (float*)carve((size_t)BATCH * NSP * 4);
  float* xbar  = (float*)carve((size_t)BATCH * CIN * 4);
  float* xg    = (float*)carve((size_t)BATCH * CIN * 4);
  float* syb   = (float*)carve((size_t)BATCH * CINT * 4);
  float* spool = (float*)carve((size_t)BATCH * CIN * 4);
  (void)ws_size; (void)in_sizes; (void)n_in; (void)out_size;

  hipMemsetAsync(abar, 0, (size_t)BATCH * NSP * 4, stream);
  hipMemsetAsync(xbar, 0, (size_t)BATCH * CIN * 4, stream);
  hipMemsetAsync(xg,   0, (size_t)BATCH * CIN * 4, stream);

  k_transpose<<<dim3(52, 8, 16), 256, 0, stream>>>(x, xt, xbar);
  k_wconv<<<1024, 256, 0, stream>>>(th_w, ph_w, wb);
  k_proj<<<1664, 256, 0, stream>>>(xt, wb, th_b, ph_b, th, ph);
  k_fgemm<<<2704, 256, 0, stream>>>(th, ph, eb, psum);
  k_abar<<<dim3(32, 16), 256, 0, stream>>>(eb, psum, abar);
  k_xg<<<dim3(16, 16), 128, 0, stream>>>(xt, abar, xg);
  k_ybar<<<512, 64, 0, stream>>>(g_w, g_b, xg, syb);
  k_spool<<<1024, 64, 0, stream>>>(w_w, w_b, xbar, syb, spool);
  k_out<<<16, 64, 0, stream>>>(spool, fc_w, fc_b, out);
}

// Round 13
// 292.297 us; speedup vs baseline: 1.0720x; 1.0222x over previous
//
#include <hip/hip_runtime.h>
#include <hip/hip_bf16.h>

// ---------------------------------------------------------------------------
// NonLocal block + FC, MI355X (gfx950).
// out = (mean_n(x) + w_w @ ybar + w_b) @ fc_w^T + fc_b
//   ybar = g_w @ xg + g_b ;  xg[b,c] = sum_n abar[b,n] x[b,c,n]
//   abar[b,m] = mean_n softmax_row(f)[n,m],  f = theta @ phi^T
// |f| <~ 60 -> exp without max-subtraction is fp32-safe; e stored bf16.
// R5: XCD remaps. R6: K-slot XOR swizzle (conflicts 6.8M->0). R7: 2-phase
// dbuf 128^2 GEMM core (structure ceiling; R8 vmcnt / R9 256^2 / R11 pad-skip
// all neutral-or-worse). R10: short8 tail + 1-phase epilogues. R12: recip
// fused into k_abar. R13: dispatch merges - wconv + abar/xg zeroing folded
// into k_transpose extra blocks; 12 -> 9 dispatches (~5 us/gap measured).
// ---------------------------------------------------------------------------

#define BATCH 16
#define CIN   1024
#define CINT  512
#define NSP   1568      // 8*14*14
#define NPAD  1664      // 13*128
#define NTIL  13
#define NCLS  13

using bf16 = __hip_bfloat16;
typedef __attribute__((ext_vector_type(8))) short short8;
typedef __attribute__((ext_vector_type(4))) float f32x4;

#define DEVI static __device__ __forceinline__

DEVI void gload16(const void* g, void* l) {
  __builtin_amdgcn_global_load_lds((const __attribute__((address_space(1))) void*)g,
                                   (__attribute__((address_space(3))) void*)l, 16, 0, 0);
}

DEVI float wave_sum(float v) {
#pragma unroll
  for (int m = 32; m; m >>= 1) v += __shfl_xor(v, m);
  return v;
}

DEVI short f2bf(float f) {
  union { __hip_bfloat16 h; short s; } u;
  u.h = __float2bfloat16(f);
  return u.s;
}
DEVI float bf2f(short s) {
  union { float f; unsigned u; } x;
  x.u = ((unsigned)(unsigned short)s) << 16;
  return x.f;
}

// ---- K1: transpose x -> xt bf16, fused xbar; extra x==52 blocks do the
// theta/phi weight bf16 conversion + zero abar/xg (dispatch merges).
// grid (53, 8, 16) block 256. n-tiles 49..51 are all-pad (zero-filled).
__global__ __launch_bounds__(256) void k_transpose(const float* __restrict__ x,
                                                   bf16* __restrict__ xt,
                                                   float* __restrict__ xbar,
                                                   const float* __restrict__ thw,
                                                   const float* __restrict__ phw,
                                                   bf16* __restrict__ wb,
                                                   float* __restrict__ abar,
                                                   float* __restrict__ xg) {
  __shared__ float t[128 * 37];
  const int tid = threadIdx.x;
  if (blockIdx.x == 52) {
    // ---- merged: wconv slice + abar/xg zeroing ----
    const int chunk = blockIdx.z * 8 + blockIdx.y;        // 0..127
    const int i4 = chunk * 8192 + tid * 32;               // 8 float4s/thread
    const float* src = (i4 < 512 * 1024) ? (thw + i4) : (phw + (i4 - 512 * 1024));
#pragma unroll
    for (int k = 0; k < 8; ++k) {
      const float4 v = *(const float4*)(src + k * 4);
      const int o = i4 + k * 4;
      wb[o + 0] = __float2bfloat16(v.x);
      wb[o + 1] = __float2bfloat16(v.y);
      wb[o + 2] = __float2bfloat16(v.z);
      wb[o + 3] = __float2bfloat16(v.w);
    }
    // zero abar (25088 floats) and xg (16384 floats); 32768 threads total
    const int w = chunk * 256 + tid;
#pragma unroll 2
    for (int i = w; i < 25088 + 16384; i += 128 * 256) {
      if (i < 25088) abar[i] = 0.f;
      else           xg[i - 25088] = 0.f;
    }
    return;
  }
  const int b = blockIdx.z;
  const int n0 = blockIdx.x * 32;
  const int c0 = blockIdx.y * 128;
  const int lane = tid & 63;
  const float* xb = x + (size_t)b * CIN * NSP;
  const bool pad = (n0 >= NSP);
#pragma unroll
  for (int it = 0; it < 4; ++it) {
    const int slot = it * 256 + tid;
    const int cr = slot >> 3;       // 0..127
    const int q = slot & 7;         // 0..7
    float4 v = {0.f, 0.f, 0.f, 0.f};
    if (!pad) v = *(const float4*)(xb + (size_t)(c0 + cr) * NSP + n0 + q * 4);
    t[cr * 37 + q * 4 + 0] = v.x;
    t[cr * 37 + q * 4 + 1] = v.y;
    t[cr * 37 + q * 4 + 2] = v.z;
    t[cr * 37 + q * 4 + 3] = v.w;
    float s = v.x + v.y + v.z + v.w;
    s += __shfl_xor(s, 1);
    s += __shfl_xor(s, 2);
    s += __shfl_xor(s, 4);
    if ((lane & 7) == 0 && !pad)
      atomicAdd(&xbar[b * CIN + c0 + cr], s * (1.0f / NSP));
  }
  __syncthreads();
  bf16* xo = xt + (size_t)b * NPAD * CIN;
#pragma unroll
  for (int it = 0; it < 2; ++it) {
    const int slot = it * 256 + tid;
    const int n = slot >> 4;        // 0..31
    const int seg = slot & 15;      // 0..15
    short8 o;
#pragma unroll
    for (int k = 0; k < 8; ++k) o[k] = f2bf(t[(seg * 8 + k) * 37 + n]);
    *(short8*)(xo + (size_t)(n0 + n) * CIN + c0 + seg * 8) = o;
  }
}

// ---- shared 128x128 bf16 BT-GEMM core: R6 swizzle + R7 2-phase dbuf --------
// LDS slot (row, kc) holds global (row, kc ^ ((row>>1)&3)); staging keeps
// gload_lds dest LINEAR and pre-swizzles the per-lane GLOBAL column; reads
// apply the same involution (lane-only expressions, zero extra VALU).
// Double buffer: lds[0..8191] = buf0 (A|B), lds[8192..16383] = buf1 (A|B).
template <int LDK>
DEVI void gemm128_bt(const bf16* Ag, const bf16* Bg, bf16* lds,
                     f32x4 acc[4][4]) {
  const int tid = threadIdx.x;
  const int lane = tid & 63;
  const int w = tid >> 6;
  const int wr = (w >> 1) * 64;
  const int wc = (w & 1) * 64;
  const int kc_src8 = ((lane & 3) ^ ((lane >> 3) & 3)) * 8;
  const int kc_rd8 = (((lane >> 4) ^ ((lane >> 1) & 3))) * 8;
  constexpr int NT = LDK / 32;   // 32 (proj) or 16 (fgemm), even

  auto STAGE = [&](int buf, int ks) {
    bf16* lA = lds + buf * 8192;
    bf16* lB = lA + 4096;
#pragma unroll
    for (int it = 0; it < 2; ++it) {
      const int ch = w * 64 + it * 256 + lane;
      const int row = ch >> 2;
      const int lbase = (w * 64 + it * 256) * 8;   // wave-uniform LDS base
      gload16(Ag + (size_t)row * LDK + ks * 32 + kc_src8, lA + lbase);
      gload16(Bg + (size_t)row * LDK + ks * 32 + kc_src8, lB + lbase);
    }
  };
  auto COMPUTE = [&](int buf) {
    const bf16* lA = lds + buf * 8192;
    const bf16* lB = lA + 4096;
    short8 af[4], bfr[4];
#pragma unroll
    for (int i = 0; i < 4; ++i)
      af[i] = *(const short8*)(lA + (wr + i * 16 + (lane & 15)) * 32 + kc_rd8);
#pragma unroll
    for (int i = 0; i < 4; ++i)
      bfr[i] = *(const short8*)(lB + (wc + i * 16 + (lane & 15)) * 32 + kc_rd8);
#pragma unroll
    for (int m = 0; m < 4; ++m)
#pragma unroll
      for (int n = 0; n < 4; ++n)
        acc[m][n] = __builtin_amdgcn_mfma_f32_16x16x32_bf16(af[m], bfr[n], acc[m][n], 0, 0, 0);
  };

  STAGE(0, 0);
  __syncthreads();
  int ks = 0;
#pragma unroll 1
  while (ks < NT - 2) {
    STAGE(1, ks + 1);
    COMPUTE(0);
    __syncthreads();
    STAGE(0, ks + 2);
    COMPUTE(1);
    __syncthreads();
    ks += 2;
  }
  STAGE(1, NT - 1);
  COMPUTE(0);
  __syncthreads();
  COMPUTE(1);
  // no trailing sync: callers barrier before reusing lds.
}

// ---- K3: theta/phi projections. 1-D grid 1664, XCD-aware decode ------------
// Single-phase epilogue: all 4 waves stage their quadrant into the full
// 128x128 (32 KB) smem concurrently, then one coalesced store pass.
__global__ __launch_bounds__(256) void k_proj(const bf16* __restrict__ xt,
                                              const bf16* __restrict__ wb,
                                              const float* __restrict__ thb,
                                              const float* __restrict__ phb,
                                              bf16* __restrict__ th,
                                              bf16* __restrict__ ph) {
  __shared__ bf16 smem[16384];  // 32 KB: dbuf in GEMM, full 128x128 stage after
  const int id = blockIdx.x;          // 0..1663
  const int rcls = id & 7;
  const int q = id >> 3;              // 0..207
  const int bm = (q >> 3) * 8 + rcls; // 0..207, XCD = bm % 8
  const int bo = q & 7;               // 0..7

  f32x4 acc[4][4];
  const f32x4 z = {0.f, 0.f, 0.f, 0.f};
#pragma unroll
  for (int m = 0; m < 4; ++m)
#pragma unroll
    for (int n = 0; n < 4; ++n) acc[m][n] = z;

  gemm128_bt<CIN>(xt + (size_t)bm * 128 * CIN, wb + (size_t)bo * 128 * CIN,
                  smem, acc);

  const int tid = threadIdx.x;
  const int lane = tid & 63;
  const int w = tid >> 6;
  const int wr = (w >> 1) * 64;
  const int wc = (w & 1) * 64;
  const float* bias = (bo < 4) ? thb : phb;
  bf16* outb = (bo < 4) ? th : ph;
  const int obase = (bo & 3) * 128;
  __syncthreads();                    // GEMM lds reads done
#pragma unroll
  for (int m = 0; m < 4; ++m)
#pragma unroll
    for (int n = 0; n < 4; ++n) {
      const int col = wc + n * 16 + (lane & 15);
      const float bv = bias[obase + col];
#pragma unroll
      for (int j = 0; j < 4; ++j) {
        const int row = wr + m * 16 + (lane >> 4) * 4 + j;   // 0..127
        smem[row * 128 + (col ^ ((row & 7) << 3))] =
            __float2bfloat16(acc[m][n][j] + bv);
      }
    }
  __syncthreads();
#pragma unroll
  for (int it = 0; it < 8; ++it) {
    const int slot = it * 256 + tid;
    const int r = slot >> 4;          // 0..127
    const int seg = slot & 15;
    const short8 v = *(const short8*)(smem + r * 128 + ((seg ^ (r & 7)) << 3));
    *(short8*)(outb + (size_t)(bm * 128 + r) * CINT + obase + seg * 8) = v;
  }
}

// ---- K4: e = exp(theta @ phi^T) bf16 + per-tile row sums -------------------
// 1-D grid 2704, XCD-aware decode: batches {b: b%8==r} on XCD r.
// Single-phase epilogue: all 4 waves exp+stage concurrently (rsum2 slots
// disjoint: [w&1][(w>>1)*64 + lr]).
__global__ __launch_bounds__(256) void k_fgemm(const bf16* __restrict__ th,
                                               const bf16* __restrict__ ph,
                                               bf16* __restrict__ eb,
                                               float* __restrict__ psum) {
  __shared__ bf16 smem[16384];
  __shared__ float rsum2[2][128];
  const int id = blockIdx.x;          // 0..2703
  const int rcls = id & 7;
  const int q = id >> 3;              // 0..337
  const int bloc = q / 169;           // 0..1
  const int t = q - bloc * 169;       // 0..168
  const int b = bloc * 8 + rcls;      // 0..15, XCD = b % 8
  const int bm = t / 13;
  const int bn = t - bm * 13;

  f32x4 acc[4][4];
  const f32x4 z = {0.f, 0.f, 0.f, 0.f};
#pragma unroll
  for (int m = 0; m < 4; ++m)
#pragma unroll
    for (int n = 0; n < 4; ++n) acc[m][n] = z;

  gemm128_bt<CINT>(th + ((size_t)b * NPAD + bm * 128) * CINT,
                   ph + ((size_t)b * NPAD + bn * 128) * CINT,
                   smem, acc);

  const int tid = threadIdx.x;
  const int lane = tid & 63;
  const int w = tid >> 6;
  const int wr = (w >> 1) * 64;
  const int wc = (w & 1) * 64;
  bf16* ebb = eb + ((size_t)b * NPAD + bm * 128) * NPAD + bn * 128;
  __syncthreads();                    // GEMM lds reads done
#pragma unroll
  for (int m = 0; m < 4; ++m)
#pragma unroll
    for (int j = 0; j < 4; ++j) {
      const int row = wr + m * 16 + (lane >> 4) * 4 + j;     // 0..127
      float ps = 0.f;
#pragma unroll
      for (int n = 0; n < 4; ++n) {
        const int col = wc + n * 16 + (lane & 15);
        const float ev = __expf(acc[m][n][j]);
        smem[row * 128 + (col ^ ((row & 7) << 3))] = __float2bfloat16(ev);
        if (bn * 128 + col < NSP) ps += ev;                  // mask pad columns
      }
      ps += __shfl_xor(ps, 1);
      ps += __shfl_xor(ps, 2);
      ps += __shfl_xor(ps, 4);
      ps += __shfl_xor(ps, 8);
      if ((lane & 15) == 0) rsum2[w & 1][row] = ps;
    }
  __syncthreads();
  if (tid < 128)
    psum[((size_t)b * NTIL + bn) * NPAD + bm * 128 + tid] =
        rsum2[0][tid] + rsum2[1][tid];
#pragma unroll
  for (int it = 0; it < 8; ++it) {
    const int slot = it * 256 + tid;
    const int r = slot >> 4;          // 0..127
    const int seg = slot & 15;
    const short8 v = *(const short8*)(smem + r * 128 + ((seg ^ (r & 7)) << 3));
    *(short8*)(ebb + (size_t)r * NPAD + seg * 8) = v;
  }
}

// ---- K5: abar[b][m] = (1/N) sum_n e[n,m] / rowsum[n]  (recip fused) --------
// grid (32, 16): x = n-slice of 49 rows (32*49 == 1568), y = b.
// threads 0..195 each own 8 m's (196*8 == 1568 exact).
__global__ void k_abar(const bf16* __restrict__ eb, const float* __restrict__ psum,
                       float* __restrict__ abar) {
  __shared__ float srinv[49];
  const int b = blockIdx.y;
  const int n0 = blockIdx.x * 49;
  const int tid = threadIdx.x;
  if (tid < 49) {
    float s = 0.f;
#pragma unroll
    for (int t = 0; t < NTIL; ++t)
      s += psum[((size_t)b * NTIL + t) * NPAD + n0 + tid];
    srinv[tid] = 1.0f / s;
  }
  __syncthreads();
  const int m0 = tid * 8;
  if (m0 >= NSP) return;
  const bf16* fb = eb + (size_t)b * NPAD * NPAD;
  float a[8];
#pragma unroll
  for (int k = 0; k < 8; ++k) a[k] = 0.f;
#pragma unroll 1
  for (int n = n0; n < n0 + 49; ++n) {
    const float iS = srinv[n - n0];
    const short8 v = *(const short8*)(fb + (size_t)n * NPAD + m0);
#pragma unroll
    for (int k = 0; k < 8; ++k) a[k] += bf2f(v[k]) * iS;
  }
#pragma unroll
  for (int k = 0; k < 8; ++k)
    atomicAdd(&abar[b * NSP + m0 + k], a[k] * (1.0f / NSP));
}

// ---- K6: xg[b][c] = sum_n abar[b][n] * xt[b][n][c]  (short8 loads) ---------
// grid (16, 16): x = n-slice of 98 rows, y = b; block 128, 8 c's/thread.
__global__ __launch_bounds__(128) void k_xg(const bf16* __restrict__ xt,
                                            const float* __restrict__ abar,
                                            float* __restrict__ xg) {
  const int b = blockIdx.y;
  const int n0 = blockIdx.x * 98;
  const int c0 = threadIdx.x * 8;     // 128*8 == 1024 exact
  const bf16* xb = xt + (size_t)b * NPAD * CIN;
  float a[8];
#pragma unroll
  for (int k = 0; k < 8; ++k) a[k] = 0.f;
#pragma unroll 1
  for (int n = n0; n < n0 + 98; ++n) {
    const float wgt = abar[b * NSP + n];
    const short8 v = *(const short8*)(xb + (size_t)n * CIN + c0);
#pragma unroll
    for (int k = 0; k < 8; ++k) a[k] += bf2f(v[k]) * wgt;
  }
#pragma unroll
  for (int k = 0; k < 8; ++k)
    atomicAdd(&xg[b * CIN + c0 + k], a[k]);
}

// ---- K7a: ybar[b][d] = g_w[d,:] @ xg[b,:] + g_b[d] -------------------------
__global__ __launch_bounds__(64) void k_ybar(const float* __restrict__ gw,
                                             const float* __restrict__ gb,
                                             const float* __restrict__ xg,
                                             float* __restrict__ syb) {
  const int d = blockIdx.x;          // 512 blocks
  const int lane = threadIdx.x;
  const float4* wr = (const float4*)(gw + (size_t)d * CIN);
  float4 wv[4];
#pragma unroll
  for (int k = 0; k < 4; ++k) wv[k] = wr[k * 64 + lane];
  const float bv = gb[d];
#pragma unroll 1
  for (int b = 0; b < BATCH; ++b) {
    const float4* xr = (const float4*)(xg + (size_t)b * CIN);
    float s = 0.f;
#pragma unroll
    for (int k = 0; k < 4; ++k) {
      const float4 xv = xr[k * 64 + lane];
      s += wv[k].x * xv.x + wv[k].y * xv.y + wv[k].z * xv.z + wv[k].w * xv.w;
    }
    s = wave_sum(s);
    if (lane == 0) syb[b * CINT + d] = s + bv;
  }
}

// ---- K7b: spool[b][c] = xbar + w_b + w_w[c,:] @ ybar[b,:] ------------------
__global__ __launch_bounds__(64) void k_spool(const float* __restrict__ ww,
                                              const float* __restrict__ wbias,
                                              const float* __restrict__ xbar,
                                              const float* __restrict__ syb,
                                              float* __restrict__ spool) {
  const int c = blockIdx.x;          // 1024 blocks
  const int lane = threadIdx.x;
  const float4* wr = (const float4*)(ww + (size_t)c * CINT);
  float4 wv[2];
#pragma unroll
  for (int k = 0; k < 2; ++k) wv[k] = wr[k * 64 + lane];
  const float bv = wbias[c];
#pragma unroll 1
  for (int b = 0; b < BATCH; ++b) {
    const float4* yr = (const float4*)(syb + (size_t)b * CINT);
    float s = 0.f;
#pragma unroll
    for (int k = 0; k < 2; ++k) {
      const float4 yv = yr[k * 64 + lane];
      s += wv[k].x * yv.x + wv[k].y * yv.y + wv[k].z * yv.z + wv[k].w * yv.w;
    }
    s = wave_sum(s);
    if (lane == 0) spool[b * CIN + c] = s + bv + xbar[b * CIN + c];
  }
}

// ---- K7c: out = spool @ fc_w^T + fc_b --------------------------------------
__global__ __launch_bounds__(64) void k_out(const float* __restrict__ spool,
                                            const float* __restrict__ fcw,
                                            const float* __restrict__ fcb,
                                            float* __restrict__ out) {
  const int b = blockIdx.x;          // 16 blocks
  const int lane = threadIdx.x;
  const float4* pr = (const float4*)(spool + (size_t)b * CIN);
  float4 pv[4];
#pragma unroll
  for (int k = 0; k < 4; ++k) pv[k] = pr[k * 64 + lane];
#pragma unroll 1
  for (int cls = 0; cls < NCLS; ++cls) {
    const float4* wr = (const float4*)(fcw + (size_t)cls * CIN);
    float s = 0.f;
#pragma unroll
    for (int k = 0; k < 4; ++k) {
      const float4 wv = wr[k * 64 + lane];
      s += wv.x * pv[k].x + wv.y * pv[k].y + wv.z * pv[k].z + wv.w * pv[k].w;
    }
    s = wave_sum(s);
    if (lane == 0) out[b * NCLS + cls] = s + fcb[cls];
  }
}

// ---------------------------------------------------------------------------
extern "C" void kernel_launch(void* const* d_in, const int* in_sizes, int n_in,
                              void* d_out, int out_size, void* d_ws, size_t ws_size,
                              hipStream_t stream) {
  const float* x    = (const float*)d_in[0];
  const float* g_w  = (const float*)d_in[1];
  const float* g_b  = (const float*)d_in[2];
  const float* th_w = (const float*)d_in[3];
  const float* th_b = (const float*)d_in[4];
  const float* ph_w = (const float*)d_in[5];
  const float* ph_b = (const float*)d_in[6];
  const float* w_w  = (const float*)d_in[7];
  const float* w_b  = (const float*)d_in[8];
  const float* fc_w = (const float*)d_in[9];
  const float* fc_b = (const float*)d_in[10];
  float* out = (float*)d_out;

  char* ws = (char*)d_ws;
  size_t off = 0;
  auto carve = [&](size_t bytes) {
    void* p = ws + off;
    off = (off + bytes + 255) & ~(size_t)255;
    return p;
  };
  bf16*  xt    = (bf16*)carve((size_t)BATCH * NPAD * CIN * 2);    // 54.5 MB
  bf16*  wb    = (bf16*)carve((size_t)1024 * 1024 * 2);           //  2 MB
  bf16*  th    = (bf16*)carve((size_t)BATCH * NPAD * CINT * 2);   // 27.3 MB
  bf16*  ph    = (bf16*)carve((size_t)BATCH * NPAD * CINT * 2);   // 27.3 MB
  bf16*  eb    = (bf16*)carve((size_t)BATCH * NPAD * NPAD * 2);   // 88.6 MB
  float* psum  = (float*)carve((size_t)BATCH * NTIL * NPAD * 4);  //  1.4 MB
  float* abar  = (float*)carve((size_t)BATCH * NSP * 4);
  float* xbar  = (float*)carve((size_t)BATCH * CIN * 4);
  float* xg    = (float*)carve((size_t)BATCH * CIN * 4);
  float* syb   = (float*)carve((size_t)BATCH * CINT * 4);
  float* spool = (float*)carve((size_t)BATCH * CIN * 4);
  (void)ws_size; (void)in_sizes; (void)n_in; (void)out_size;

  // xbar must be zeroed before k_transpose (it accumulates into it);
  // abar/xg are zeroed inside k_transpose's merged blocks.
  hipMemsetAsync(xbar, 0, (size_t)BATCH * CIN * 4, stream);

  k_transpose<<<dim3(53, 8, 16), 256, 0, stream>>>(x, xt, xbar, th_w, ph_w, wb,
                                                   abar, xg);
  k_proj<<<1664, 256, 0, stream>>>(xt, wb, th_b, ph_b, th, ph);
  k_fgemm<<<2704, 256, 0, stream>>>(th, ph, eb, psum);
  k_abar<<<dim3(32, 16), 256, 0, stream>>>(eb, psum, abar);
  k_xg<<<dim3(16, 16), 128, 0, stream>>>(xt, abar, xg);
  k_ybar<<<512, 64, 0, stream>>>(g_w, g_b, xg, syb);
  k_spool<<<1024, 64, 0, stream>>>(w_w, w_b, xbar, syb, spool);
  k_out<<<16, 64, 0, stream>>>(spool, fc_w, fc_b, out);
}